// Round 2
// baseline (238.981 us; speedup 1.0000x reference)
//
#include <hip/hip_runtime.h>
#include <math.h>

// Problem constants (fixed by setup_inputs): B=4, H=W=D=128, C=2, fp32.
#define BN 4
#define HN 128
#define WN 128
#define DN 128
#define TOTAL (BN * HN * WN * DN)

// One thread per output voxel (b,i,j,k); computes both channels (float2).
// Coordinate path in DOUBLE to mirror the harness's NumPy float64 reference:
// the reference's clipping convention is discontinuous at volume edges, so
// floor() decisions must match the fp64 reference bit-for-bit (fp32 coord
// math flips boundary voxels -> O(1) absmax error; measured 2.1 in round 1).
// Input gathers use the reference's (faithfully weird) flat-index convention:
//   idx = b*H*W*D + y*W + z*(W*H) + x
__global__ __launch_bounds__(256) void st_trilerp_kernel(
    const float* __restrict__ image,   // [B*H*W*D, 2] viewed flat
    const float* __restrict__ theta,   // [B, 3, 4]
    float* __restrict__ out)           // [B*H*W*D, 2]
{
    const int t = blockIdx.x * blockDim.x + threadIdx.x;
    if (t >= TOTAL) return;

    const int k = t & (DN - 1);          // D index  (z-grid)
    const int j = (t >> 7) & (WN - 1);   // W index  (x-grid)
    const int i = (t >> 14) & (HN - 1);  // H index  (y-grid)
    const int b = t >> 21;               // batch

    // np.linspace(-1, 1, 128) float64: v = i*(2/127) - 1, endpoint set EXACTLY.
    const double step = 2.0 / 127.0;
    const double X = (j == WN - 1) ? 1.0 : (double)j * step - 1.0;
    const double Y = (i == HN - 1) ? 1.0 : (double)i * step - 1.0;
    const double Z = (k == DN - 1) ? 1.0 : (double)k * step - 1.0;

    const float* th = theta + b * 12;   // b is wave-uniform -> scalar loads
    // einsum in float64, sequential accumulation order j=0..3
    const double xt = (((double)th[0] * X + (double)th[1] * Y) + (double)th[2]  * Z) + (double)th[3];
    const double yt = (((double)th[4] * X + (double)th[5] * Y) + (double)th[6]  * Z) + (double)th[7];
    const double zt = (((double)th[8] * X + (double)th[9] * Y) + (double)th[10] * Z) + (double)th[11];

    // map [-1,1] -> pixel coords using FULL extent (original convention), fp64
    const double x = (0.5 * (xt + 1.0)) * (double)WN;
    const double y = (0.5 * (yt + 1.0)) * (double)HN;
    const double z = (0.5 * (zt + 1.0)) * (double)DN;

    // floor, +1, then clip (x1 derives from UNclipped x0+1)
    const int x0u = (int)floor(x);
    const int y0u = (int)floor(y);
    const int z0u = (int)floor(z);
    const int x0 = min(max(x0u,     0), WN - 1);
    const int x1 = min(max(x0u + 1, 0), WN - 1);
    const int y0 = min(max(y0u,     0), HN - 1);
    const int y1 = min(max(y0u + 1, 0), HN - 1);
    const int z0 = min(max(z0u,     0), DN - 1);
    const int z1 = min(max(z0u + 1, 0), DN - 1);

    const int base = b * (HN * WN * DN);
    const int b00 = base + y0 * WN + z0 * (WN * HN);
    const int b10 = base + y1 * WN + z0 * (WN * HN);
    const int b01 = base + y0 * WN + z1 * (WN * HN);
    const int b11 = base + y1 * WN + z1 * (WN * HN);

    const float2* __restrict__ img2 = (const float2*)image;
    const float2 pa = img2[b00 + x0];
    const float2 pb = img2[b10 + x0];
    const float2 pc = img2[b00 + x1];
    const float2 pd = img2[b10 + x1];
    const float2 pe = img2[b01 + x0];
    const float2 pf = img2[b11 + x0];
    const float2 pg = img2[b01 + x1];
    const float2 ph = img2[b11 + x1];

    // weights from CLIPPED coords in fp64; z-weight of e..h group is (z1f-z0f)
    const double x0f = (double)x0, x1f = (double)x1;
    const double y0f = (double)y0, y1f = (double)y1;
    const double z0f = (double)z0, z1f = (double)z1;

    const double wx0 = x1f - x, wx1 = x - x0f;
    const double wy0 = y1f - y, wy1 = y - y0f;
    const double wz0 = z1f - z, wzA = z1f - z0f;

    const float wa = (float)(wx0 * wy0 * wz0);
    const float wb = (float)(wx0 * wy1 * wz0);
    const float wc = (float)(wx1 * wy0 * wz0);
    const float wd = (float)(wx1 * wy1 * wz0);
    const float we = (float)(wx0 * wy0 * wzA);
    const float wf = (float)(wx0 * wy1 * wzA);
    const float wg = (float)(wx1 * wy0 * wzA);
    const float wh = (float)(wx1 * wy1 * wzA);

    float2 o;
    o.x = wa * pa.x + wb * pb.x + wc * pc.x + wd * pd.x
        + we * pe.x + wf * pf.x + wg * pg.x + wh * ph.x;
    o.y = wa * pa.y + wb * pb.y + wc * pc.y + wd * pd.y
        + we * pe.y + wf * pf.y + wg * pg.y + wh * ph.y;

    ((float2*)out)[t] = o;
}

extern "C" void kernel_launch(void* const* d_in, const int* in_sizes, int n_in,
                              void* d_out, int out_size, void* d_ws, size_t ws_size,
                              hipStream_t stream) {
    const float* image = (const float*)d_in[0];
    const float* theta = (const float*)d_in[1];
    float* out = (float*)d_out;

    const int threads = 256;
    const int blocks = TOTAL / threads;  // 8,388,608 / 256 = 32768
    st_trilerp_kernel<<<blocks, threads, 0, stream>>>(image, theta, out);
}

// Round 3
// 149.491 us; speedup vs baseline: 1.5986x; 1.5986x over previous
//
#include <hip/hip_runtime.h>
#include <math.h>

// Problem constants (fixed by setup_inputs): B=4, H=W=D=128, C=2, fp32.
#define BN 4
#define HN 128
#define WN 128
#define DN 128

// Block = 16x16 (j,k) tile at fixed (b,i). Compute phase maps lanes with
// jj FASTEST: j drives x, the contiguous axis of the image layout
//   idx = b*H*W*D + y*W + z*(W*H) + x
// so a 16-lane segment gathers a ~128B contiguous run (vs 16 distinct lines
// with the round-1 k-fastest mapping -> measured 28 TB/s L2-side traffic,
// at the L2 request ceiling). Output wants k fastest -> transpose via LDS.
//
// Coordinate path in DOUBLE to mirror the harness's NumPy float64 reference
// (clip convention is discontinuous at edges; fp32 coord math flips boundary
// voxels -> absmax 2.1 in round 1).
__global__ __launch_bounds__(256) void st_trilerp_kernel(
    const float* __restrict__ image,   // [B*H*W*D, 2] viewed flat
    const float* __restrict__ theta,   // [B, 3, 4]
    float* __restrict__ out)           // [B*H*W*D, 2]
{
    const int bi = blockIdx.z;         // b*H + i  (uniform per block)
    const int b  = bi >> 7;
    const int i  = bi & (HN - 1);
    const int j0 = blockIdx.y << 4;
    const int k0 = blockIdx.x << 4;

    const int tid = threadIdx.x;
    const int jj = tid & 15;           // x-axis fastest across lanes
    const int kk = tid >> 4;
    const int j = j0 + jj;
    const int k = k0 + kk;

    // np.linspace(-1, 1, 128) float64: v = i*(2/127) - 1, endpoint EXACT.
    const double step = 2.0 / 127.0;
    const double X = (j == WN - 1) ? 1.0 : (double)j * step - 1.0;
    const double Y = (i == HN - 1) ? 1.0 : (double)i * step - 1.0;
    const double Z = (k == DN - 1) ? 1.0 : (double)k * step - 1.0;

    const float* th = theta + b * 12;  // b uniform -> scalar loads
    const double xt = (((double)th[0] * X + (double)th[1] * Y) + (double)th[2]  * Z) + (double)th[3];
    const double yt = (((double)th[4] * X + (double)th[5] * Y) + (double)th[6]  * Z) + (double)th[7];
    const double zt = (((double)th[8] * X + (double)th[9] * Y) + (double)th[10] * Z) + (double)th[11];

    // map [-1,1] -> pixel coords using FULL extent (original convention)
    const double x = (0.5 * (xt + 1.0)) * (double)WN;
    const double y = (0.5 * (yt + 1.0)) * (double)HN;
    const double z = (0.5 * (zt + 1.0)) * (double)DN;

    // floor, +1, then clip (x1 derives from UNclipped x0+1)
    const int x0u = (int)floor(x);
    const int y0u = (int)floor(y);
    const int z0u = (int)floor(z);
    const int x0 = min(max(x0u,     0), WN - 1);
    const int x1 = min(max(x0u + 1, 0), WN - 1);
    const int y0 = min(max(y0u,     0), HN - 1);
    const int y1 = min(max(y0u + 1, 0), HN - 1);
    const int z0 = min(max(z0u,     0), DN - 1);
    const int z1 = min(max(z0u + 1, 0), DN - 1);

    const int base = b * (HN * WN * DN);
    const int b00 = base + y0 * WN + z0 * (WN * HN);
    const int b10 = base + y1 * WN + z0 * (WN * HN);
    const int b01 = base + y0 * WN + z1 * (WN * HN);
    const int b11 = base + y1 * WN + z1 * (WN * HN);

    const float2* __restrict__ img2 = (const float2*)image;
    const float2 pa = img2[b00 + x0];
    const float2 pb = img2[b10 + x0];
    const float2 pc = img2[b00 + x1];
    const float2 pd = img2[b10 + x1];
    const float2 pe = img2[b01 + x0];
    const float2 pf = img2[b11 + x0];
    const float2 pg = img2[b01 + x1];
    const float2 ph = img2[b11 + x1];

    // weights from CLIPPED coords in fp64; z-weight of e..h group is (z1f-z0f)
    const double x0f = (double)x0, x1f = (double)x1;
    const double y0f = (double)y0, y1f = (double)y1;
    const double z0f = (double)z0, z1f = (double)z1;

    const double wx0 = x1f - x, wx1 = x - x0f;
    const double wy0 = y1f - y, wy1 = y - y0f;
    const double wz0 = z1f - z, wzA = z1f - z0f;

    const float wa = (float)(wx0 * wy0 * wz0);
    const float wb = (float)(wx0 * wy1 * wz0);
    const float wc = (float)(wx1 * wy0 * wz0);
    const float wd = (float)(wx1 * wy1 * wz0);
    const float we = (float)(wx0 * wy0 * wzA);
    const float wf = (float)(wx0 * wy1 * wzA);
    const float wg = (float)(wx1 * wy0 * wzA);
    const float wh = (float)(wx1 * wy1 * wzA);

    float2 o;
    o.x = wa * pa.x + wb * pb.x + wc * pc.x + wd * pd.x
        + we * pe.x + wf * pf.x + wg * pg.x + wh * ph.x;
    o.y = wa * pa.y + wb * pb.y + wc * pc.y + wd * pd.y
        + we * pe.y + wf * pf.y + wg * pg.y + wh * ph.y;

    // LDS transpose: computed with jj-fastest, written with kk-fastest.
    __shared__ float2 tile[16][17];    // pitch 17 float2 breaks pow-2 stride
    tile[kk][jj] = o;
    __syncthreads();

    const int kw = tid & 15;           // k fastest for coalesced writes
    const int jw = tid >> 4;
    const int oidx = (bi * WN + (j0 + jw)) * DN + (k0 + kw);
    ((float2*)out)[oidx] = tile[kw][jw];
}

extern "C" void kernel_launch(void* const* d_in, const int* in_sizes, int n_in,
                              void* d_out, int out_size, void* d_ws, size_t ws_size,
                              hipStream_t stream) {
    const float* image = (const float*)d_in[0];
    const float* theta = (const float*)d_in[1];
    float* out = (float*)d_out;

    dim3 grid(DN / 16, WN / 16, BN * HN);   // (8, 8, 512)
    st_trilerp_kernel<<<grid, 256, 0, stream>>>(image, theta, out);
}

// Round 4
// 145.094 us; speedup vs baseline: 1.6471x; 1.0303x over previous
//
#include <hip/hip_runtime.h>
#include <math.h>

// Problem constants (fixed by setup_inputs): B=4, H=W=D=128, C=2, fp32.
#define BN 4
#define HN 128
#define WN 128
#define DN 128

// Block = 16x16 (j,k) tile at fixed (b,i). Lanes mapped jj-fastest (j drives
// x, the contiguous axis of idx = b*H*W*D + y*W + z*(W*H) + x); output wants
// k-fastest -> LDS transpose before the store.
//
// Gather-pair trick: the reference's 8 taps come in 4 pairs at adjacent x
// ((pa,pc),(pb,pd),(pe,pg),(pf,ph) with x1 = x0+1 except at clips), and each
// voxel is a float2 (C=2), so one 16B float4 load fetches a whole pair.
// Clip cases ((0,0),(127,127)) are handled by loading at xb=min(x0,126) and
// cndmask-selecting halves -> always in-bounds, 4 vmem insts instead of 8.
//
// Coordinate path in DOUBLE to mirror the harness's NumPy float64 reference
// (clip convention is discontinuous at edges; fp32 coord math flips boundary
// voxels -> absmax 2.1 in round 1). Weight PRODUCTS in fp32 (continuous,
// ~1e-6 error vs 1.78 threshold); subtractions stay fp64.
__global__ __launch_bounds__(256) void st_trilerp_kernel(
    const float* __restrict__ image,   // [B*H*W*D, 2] viewed flat
    const float* __restrict__ theta,   // [B, 3, 4]
    float* __restrict__ out)           // [B*H*W*D, 2]
{
    const int bi = blockIdx.z;         // b*H + i  (uniform per block)
    const int b  = bi >> 7;
    const int i  = bi & (HN - 1);
    const int j0 = blockIdx.y << 4;
    const int k0 = blockIdx.x << 4;

    const int tid = threadIdx.x;
    const int jj = tid & 15;           // x-axis fastest across lanes
    const int kk = tid >> 4;
    const int j = j0 + jj;
    const int k = k0 + kk;

    // np.linspace(-1, 1, 128) float64: v = i*(2/127) - 1, endpoint EXACT.
    const double step = 2.0 / 127.0;
    const double X = (j == WN - 1) ? 1.0 : (double)j * step - 1.0;
    const double Y = (i == HN - 1) ? 1.0 : (double)i * step - 1.0;
    const double Z = (k == DN - 1) ? 1.0 : (double)k * step - 1.0;

    const float* th = theta + b * 12;  // b uniform -> scalar loads
    const double xt = (((double)th[0] * X + (double)th[1] * Y) + (double)th[2]  * Z) + (double)th[3];
    const double yt = (((double)th[4] * X + (double)th[5] * Y) + (double)th[6]  * Z) + (double)th[7];
    const double zt = (((double)th[8] * X + (double)th[9] * Y) + (double)th[10] * Z) + (double)th[11];

    // map [-1,1] -> pixel coords using FULL extent (original convention)
    const double x = (0.5 * (xt + 1.0)) * (double)WN;
    const double y = (0.5 * (yt + 1.0)) * (double)HN;
    const double z = (0.5 * (zt + 1.0)) * (double)DN;

    // floor, +1, then clip (x1 derives from UNclipped x0+1)
    const int x0u = (int)floor(x);
    const int y0u = (int)floor(y);
    const int z0u = (int)floor(z);
    const int x0 = min(max(x0u,     0), WN - 1);
    const int x1 = min(max(x0u + 1, 0), WN - 1);
    const int y0 = min(max(y0u,     0), HN - 1);
    const int y1 = min(max(y0u + 1, 0), HN - 1);
    const int z0 = min(max(z0u,     0), DN - 1);
    const int z1 = min(max(z0u + 1, 0), DN - 1);

    const int base = b * (HN * WN * DN);
    const int b00 = base + y0 * WN + z0 * (WN * HN);
    const int b10 = base + y1 * WN + z0 * (WN * HN);
    const int b01 = base + y0 * WN + z1 * (WN * HN);
    const int b11 = base + y1 * WN + z1 * (WN * HN);

    const float2* __restrict__ img2 = (const float2*)image;

    // (x0,x1) is always (v,v+1) for v in 0..126, or (0,0), or (127,127).
    const int xb = min(x0, WN - 2);                 // 0..126, pair in-bounds
    const bool lo0 = (x0 == xb);                    // pa/pb/pe/pf from low half?
    const bool lo1 = (x1 == xb);                    // pc/pd/pg/ph from low half?

    const float4 q00 = *(const float4*)(img2 + b00 + xb);
    const float4 q10 = *(const float4*)(img2 + b10 + xb);
    const float4 q01 = *(const float4*)(img2 + b01 + xb);
    const float4 q11 = *(const float4*)(img2 + b11 + xb);

    const float2 pa = lo0 ? make_float2(q00.x, q00.y) : make_float2(q00.z, q00.w);
    const float2 pc = lo1 ? make_float2(q00.x, q00.y) : make_float2(q00.z, q00.w);
    const float2 pb = lo0 ? make_float2(q10.x, q10.y) : make_float2(q10.z, q10.w);
    const float2 pd = lo1 ? make_float2(q10.x, q10.y) : make_float2(q10.z, q10.w);
    const float2 pe = lo0 ? make_float2(q01.x, q01.y) : make_float2(q01.z, q01.w);
    const float2 pg = lo1 ? make_float2(q01.x, q01.y) : make_float2(q01.z, q01.w);
    const float2 pf = lo0 ? make_float2(q11.x, q11.y) : make_float2(q11.z, q11.w);
    const float2 ph = lo1 ? make_float2(q11.x, q11.y) : make_float2(q11.z, q11.w);

    // weight FACTORS in fp64 (cancellation must match np), products in fp32
    const float wx0 = (float)((double)x1 - x), wx1 = (float)(x - (double)x0);
    const float wy0 = (float)((double)y1 - y), wy1 = (float)(y - (double)y0);
    const float wz0 = (float)((double)z1 - z);
    const float wzA = (float)(z1 - z0);

    const float wa = wx0 * wy0 * wz0;
    const float wb = wx0 * wy1 * wz0;
    const float wc = wx1 * wy0 * wz0;
    const float wd = wx1 * wy1 * wz0;
    const float we = wx0 * wy0 * wzA;
    const float wf = wx0 * wy1 * wzA;
    const float wg = wx1 * wy0 * wzA;
    const float wh = wx1 * wy1 * wzA;

    float2 o;
    o.x = wa * pa.x + wb * pb.x + wc * pc.x + wd * pd.x
        + we * pe.x + wf * pf.x + wg * pg.x + wh * ph.x;
    o.y = wa * pa.y + wb * pb.y + wc * pc.y + wd * pd.y
        + we * pe.y + wf * pf.y + wg * pg.y + wh * ph.y;

    // LDS transpose: computed with jj-fastest, written with kk-fastest.
    __shared__ float2 tile[16][17];    // pitch 17 float2 breaks pow-2 stride
    tile[kk][jj] = o;
    __syncthreads();

    const int kw = tid & 15;           // k fastest for coalesced writes
    const int jw = tid >> 4;
    const int oidx = (bi * WN + (j0 + jw)) * DN + (k0 + kw);
    ((float2*)out)[oidx] = tile[kw][jw];
}

extern "C" void kernel_launch(void* const* d_in, const int* in_sizes, int n_in,
                              void* d_out, int out_size, void* d_ws, size_t ws_size,
                              hipStream_t stream) {
    const float* image = (const float*)d_in[0];
    const float* theta = (const float*)d_in[1];
    float* out = (float*)d_out;

    dim3 grid(DN / 16, WN / 16, BN * HN);   // (8, 8, 512)
    st_trilerp_kernel<<<grid, 256, 0, stream>>>(image, theta, out);
}